// Round 1
// baseline (921.155 us; speedup 1.0000x reference)
//
#include <hip/hip_runtime.h>
#include <hip/hip_bf16.h>

#define N_TOK 2048
#define H_DIM 2048
#define V_DIM 32000
#define BETA 0.5f

typedef __attribute__((ext_vector_type(8))) short short8;
typedef __attribute__((ext_vector_type(4))) float f32x4;

__device__ __forceinline__ float bf2f(short s) {
  unsigned int u = ((unsigned int)(unsigned short)s) << 16;
  return __uint_as_float(u);
}
__device__ __forceinline__ short f2b(float f) {
  __hip_bfloat16 h = __float2bfloat16(f);
  return *reinterpret_cast<short*>(&h);
}

// ---------------- fp32 -> bf16 conversion (vectorized, grid-stride) -------
__global__ __launch_bounds__(256) void cvt_bf16(const float* __restrict__ s,
                                                short* __restrict__ d, int n8) {
  int stride = gridDim.x * 256;
  for (int i = blockIdx.x * 256 + threadIdx.x; i < n8; i += stride) {
    const float4* sp = reinterpret_cast<const float4*>(s) + (size_t)i * 2;
    float4 a = sp[0], b = sp[1];
    short8 o;
    o[0] = f2b(a.x); o[1] = f2b(a.y); o[2] = f2b(a.z); o[3] = f2b(a.w);
    o[4] = f2b(b.x); o[5] = f2b(b.y); o[6] = f2b(b.z); o[7] = f2b(b.w);
    *reinterpret_cast<short8*>(d + (size_t)i * 8) = o;
  }
}

// ---------------- bf16 GEMM: logits[n,v] = sum_h A[n,h]*W[v,h] ------------
#define BM 128
#define BN 128
#define BK 64

__device__ __forceinline__ void gload_lds16(const void* g, void* l) {
  __builtin_amdgcn_global_load_lds(
      (const __attribute__((address_space(1))) void*)g,
      (__attribute__((address_space(3))) void*)l, 16, 0, 0);
}

__global__ __launch_bounds__(256) void gemm_logits(
    const short* __restrict__ As, const short* __restrict__ At,
    const short* __restrict__ Ws, const short* __restrict__ Wt,
    short* __restrict__ Lgs, short* __restrict__ Lgt) {
  const short* A = blockIdx.z ? At : As;
  const short* W = blockIdx.z ? Wt : Ws;
  short* L = blockIdx.z ? Lgt : Lgs;

  __shared__ short sA[BM * BK];
  __shared__ short sB[BN * BK];

  const int tid = threadIdx.x;
  const int wave = tid >> 6, lane = tid & 63;
  const int m0 = blockIdx.y * BM;
  const int v0 = blockIdx.x * BN;
  const int wm = (wave >> 1) * 64;
  const int wn = (wave & 1) * 64;

  f32x4 acc[4][4];
#pragma unroll
  for (int i = 0; i < 4; ++i)
#pragma unroll
    for (int j = 0; j < 4; ++j) acc[i][j] = (f32x4){0.f, 0.f, 0.f, 0.f};

  const int lrow = lane & 15;
  const int lk = lane >> 4;

  for (int k0 = 0; k0 < H_DIM; k0 += BK) {
    if (k0) __syncthreads();
    // Stage 128x64 bf16 tiles. LDS dest is linear (wave-uniform base + lane*16);
    // the XOR swizzle is applied by permuting the per-lane GLOBAL source
    // (rule 21: linear dest + inverse-swz source + swz on read).
#pragma unroll
    for (int i = 0; i < 4; ++i) {
      int gbase = (wave * 4 + i) * 64;   // granule index of lane 0 (16B granules)
      int g = gbase + lane;
      int row = g >> 3, c8p = g & 7;
      int col = (c8p ^ (row & 7)) * 8;   // logical column for this physical slot
      gload_lds16(A + (size_t)(m0 + row) * H_DIM + k0 + col, &sA[gbase * 8]);
      gload_lds16(W + (size_t)(v0 + row) * H_DIM + k0 + col, &sB[gbase * 8]);
    }
    __syncthreads();  // compiler drains vmcnt(0) before s_barrier

#pragma unroll
    for (int kk = 0; kk < 2; ++kk) {
      short8 av[4], bv[4];
      int c8 = kk * 4 + lk;
#pragma unroll
      for (int f = 0; f < 4; ++f) {
        int ar = wm + f * 16 + lrow;
        av[f] = *reinterpret_cast<const short8*>(&sA[ar * 64 + ((c8 ^ (ar & 7)) * 8)]);
        int br = wn + f * 16 + lrow;
        bv[f] = *reinterpret_cast<const short8*>(&sB[br * 64 + ((c8 ^ (br & 7)) * 8)]);
      }
#pragma unroll
      for (int fm = 0; fm < 4; ++fm)
#pragma unroll
        for (int fn = 0; fn < 4; ++fn)
          acc[fm][fn] = __builtin_amdgcn_mfma_f32_16x16x32_bf16(
              av[fm], bv[fn], acc[fm][fn], 0, 0, 0);
    }
  }

  // Epilogue: C/D layout col=lane&15, row=(lane>>4)*4+j (m89-verified)
#pragma unroll
  for (int fm = 0; fm < 4; ++fm) {
#pragma unroll
    for (int fn = 0; fn < 4; ++fn) {
      int gm = m0 + wm + fm * 16 + (lane >> 4) * 4;
      int gv = v0 + wn + fn * 16 + (lane & 15);
#pragma unroll
      for (int j = 0; j < 4; ++j)
        L[(size_t)(gm + j) * V_DIM + gv] = f2b(acc[fm][fn][j]);
    }
  }
}

// ---------------- per-row logsumexp (Z = max + log(sum exp)) --------------
__global__ __launch_bounds__(256) void row_stats(const short* __restrict__ Lgs,
                                                 const short* __restrict__ Lgt,
                                                 float* __restrict__ Zq,
                                                 float* __restrict__ Zp) {
  const int n = blockIdx.x;
  const short* row = (blockIdx.y ? Lgt : Lgs) + (size_t)n * V_DIM;
  float* Z = blockIdx.y ? Zp : Zq;
  __shared__ float red[4];

  float mx = -1e30f;
  for (int v = threadIdx.x * 8; v < V_DIM; v += 2048) {
    short8 x = *reinterpret_cast<const short8*>(row + v);
#pragma unroll
    for (int j = 0; j < 8; ++j) mx = fmaxf(mx, bf2f(x[j]));
  }
#pragma unroll
  for (int o = 32; o; o >>= 1) mx = fmaxf(mx, __shfl_xor(mx, o));
  if ((threadIdx.x & 63) == 0) red[threadIdx.x >> 6] = mx;
  __syncthreads();
  mx = fmaxf(fmaxf(red[0], red[1]), fmaxf(red[2], red[3]));
  __syncthreads();

  float s = 0.f;
  for (int v = threadIdx.x * 8; v < V_DIM; v += 2048) {
    short8 x = *reinterpret_cast<const short8*>(row + v);
#pragma unroll
    for (int j = 0; j < 8; ++j) s += __expf(bf2f(x[j]) - mx);
  }
#pragma unroll
  for (int o = 32; o; o >>= 1) s += __shfl_xor(s, o);
  if ((threadIdx.x & 63) == 0) red[threadIdx.x >> 6] = s;
  __syncthreads();
  if (threadIdx.x == 0) Z[n] = mx + __logf(red[0] + red[1] + red[2] + red[3]);
}

// ---------------- JSD accumulation ----------------------------------------
__global__ __launch_bounds__(256) void jsd_kernel(const short* __restrict__ Lgs,
                                                  const short* __restrict__ Lgt,
                                                  const float* __restrict__ Zq,
                                                  const float* __restrict__ Zp,
                                                  float* __restrict__ partials) {
  const unsigned GR = V_DIM / 8;                 // 4000 granules per row
  const unsigned total = (unsigned)N_TOK * GR;   // 8,192,000
  float acc = 0.f;
  for (unsigned g = blockIdx.x * 256 + threadIdx.x; g < total;
       g += gridDim.x * 256) {
    unsigned n = g / GR;
    size_t base = (size_t)g * 8;
    short8 xs = *reinterpret_cast<const short8*>(Lgs + base);
    short8 xt = *reinterpret_cast<const short8*>(Lgt + base);
    float zq = Zq[n], zp = Zp[n];
#pragma unroll
    for (int j = 0; j < 8; ++j) {
      float lq = bf2f(xs[j]) - zq;   // student log-prob
      float lp = bf2f(xt[j]) - zp;   // teacher log-prob
      float q = __expf(lq), p = __expf(lp);
      float m = p + BETA * (q - p);
      float lm = __logf(m);
      acc += BETA * (p * (lp - lm)) + (1.f - BETA) * (q * (lq - lm));
    }
  }
#pragma unroll
  for (int o = 32; o; o >>= 1) acc += __shfl_xor(acc, o);
  __shared__ float red[4];
  if ((threadIdx.x & 63) == 0) red[threadIdx.x >> 6] = acc;
  __syncthreads();
  if (threadIdx.x == 0) partials[blockIdx.x] = red[0] + red[1] + red[2] + red[3];
}

__global__ __launch_bounds__(256) void final_reduce(const float* __restrict__ partials,
                                                    int nb, float* __restrict__ out) {
  float s = 0.f;
  for (int i = threadIdx.x; i < nb; i += 256) s += partials[i];
#pragma unroll
  for (int o = 32; o; o >>= 1) s += __shfl_xor(s, o);
  __shared__ float red[4];
  if ((threadIdx.x & 63) == 0) red[threadIdx.x >> 6] = s;
  __syncthreads();
  if (threadIdx.x == 0) out[0] = (red[0] + red[1] + red[2] + red[3]) / (float)N_TOK;
}

// ---------------- launch ---------------------------------------------------
extern "C" void kernel_launch(void* const* d_in, const int* in_sizes, int n_in,
                              void* d_out, int out_size, void* d_ws, size_t ws_size,
                              hipStream_t stream) {
  const float* s_in = (const float*)d_in[0];
  const float* t_in = (const float*)d_in[1];
  const float* w_s  = (const float*)d_in[2];
  const float* w_t  = (const float*)d_in[3];
  float* out = (float*)d_out;

  char* ws = (char*)d_ws;
  size_t off = 0;
  auto alloc = [&](size_t bytes) {
    char* p = ws + off;
    off += (bytes + 255) & ~(size_t)255;
    return p;
  };
  short* Abf_s = (short*)alloc((size_t)N_TOK * H_DIM * 2);
  short* Abf_t = (short*)alloc((size_t)N_TOK * H_DIM * 2);
  short* Wbf_s = (short*)alloc((size_t)V_DIM * H_DIM * 2);
  short* Wbf_t = (short*)alloc((size_t)V_DIM * H_DIM * 2);
  short* Lg_s  = (short*)alloc((size_t)N_TOK * V_DIM * 2);
  short* Lg_t  = (short*)alloc((size_t)N_TOK * V_DIM * 2);
  float* Zq = (float*)alloc(N_TOK * 4);
  float* Zp = (float*)alloc(N_TOK * 4);
  const int LOSS_BLOCKS = 2048;
  float* partials = (float*)alloc(LOSS_BLOCKS * 4);

  if (off > ws_size) {
    // Not enough workspace: write a recognizable sentinel so the failure mode
    // is diagnosable from the absmax error (~3e38 -> NaN-ish huge error).
    hipMemsetAsync(d_out, 0xFF, sizeof(float), stream);
    return;
  }

  cvt_bf16<<<512, 256, 0, stream>>>(s_in, Abf_s, N_TOK * H_DIM / 8);
  cvt_bf16<<<512, 256, 0, stream>>>(t_in, Abf_t, N_TOK * H_DIM / 8);
  cvt_bf16<<<2048, 256, 0, stream>>>(w_s, Wbf_s, V_DIM * H_DIM / 8);
  cvt_bf16<<<2048, 256, 0, stream>>>(w_t, Wbf_t, V_DIM * H_DIM / 8);

  gemm_logits<<<dim3(V_DIM / BN, N_TOK / BM, 2), 256, 0, stream>>>(
      Abf_s, Abf_t, Wbf_s, Wbf_t, Lg_s, Lg_t);

  row_stats<<<dim3(N_TOK, 2), 256, 0, stream>>>(Lg_s, Lg_t, Zq, Zp);

  jsd_kernel<<<LOSS_BLOCKS, 256, 0, stream>>>(Lg_s, Lg_t, Zq, Zp, partials);
  final_reduce<<<1, 256, 0, stream>>>(partials, LOSS_BLOCKS, out);
}

// Round 2
// 836.086 us; speedup vs baseline: 1.1017x; 1.1017x over previous
//
#include <hip/hip_runtime.h>
#include <hip/hip_bf16.h>

#define N_TOK 2048
#define H_DIM 2048
#define V_DIM 32000
#define BETA 0.5f

typedef __attribute__((ext_vector_type(8))) short short8;
typedef __attribute__((ext_vector_type(4))) float f32x4;

__device__ __forceinline__ float bf2f(short s) {
  unsigned int u = ((unsigned int)(unsigned short)s) << 16;
  return __uint_as_float(u);
}
__device__ __forceinline__ short f2b(float f) {
  __hip_bfloat16 h = __float2bfloat16(f);
  return *reinterpret_cast<short*>(&h);
}

// ---------------- fp32 -> bf16 conversion (vectorized, grid-stride) -------
__global__ __launch_bounds__(256) void cvt_bf16(const float* __restrict__ s,
                                                short* __restrict__ d, int n8) {
  int stride = gridDim.x * 256;
  for (int i = blockIdx.x * 256 + threadIdx.x; i < n8; i += stride) {
    const float4* sp = reinterpret_cast<const float4*>(s) + (size_t)i * 2;
    float4 a = sp[0], b = sp[1];
    short8 o;
    o[0] = f2b(a.x); o[1] = f2b(a.y); o[2] = f2b(a.z); o[3] = f2b(a.w);
    o[4] = f2b(b.x); o[5] = f2b(b.y); o[6] = f2b(b.z); o[7] = f2b(b.w);
    *reinterpret_cast<short8*>(d + (size_t)i * 8) = o;
  }
}

// ---------------- bf16 GEMM: logits[n,v] = sum_h A[n,h]*W[v,h] ------------
// BM=256, BN=128, BK=64. 512 threads = 8 waves (4M x 2N), per-wave 64x64 out.
// 3-deep LDS tile pipeline (48 KB/tile = A 32 KB + B 16 KB), counted vmcnt(6).
#define TILE_SH 24576  // shorts per tile buffer (A 16384 + B 8192)

__device__ __forceinline__ void gload_lds16(const void* g, void* l) {
  __builtin_amdgcn_global_load_lds(
      (const __attribute__((address_space(1))) void*)g,
      (__attribute__((address_space(3))) void*)l, 16, 0, 0);
}

// Stage 3 of the 6 16B-granule loads of one K-tile. Lo=0: A granules 0..1535;
// Lo=3: A granules 1536..2047 + B granules 0..1023.
// LDS dest is linear per-wave (uniform base + lane*16); the XOR swizzle is
// applied by permuting the per-lane GLOBAL source column (rule 21).
template <int Lo>
__device__ __forceinline__ void stage_tile(const short* __restrict__ A,
                                           const short* __restrict__ W,
                                           short* lds, int bufbase, int m0,
                                           int v0, int k0, int wave, int lane) {
#pragma unroll
  for (int L = Lo; L < Lo + 3; ++L) {
    const int gbase = L * 512 + wave * 64;  // wave-uniform granule base
    const int g = gbase + lane;
    if (L < 4) {  // A granule (row 0..255)
      const int row = g >> 3, c8p = g & 7;
      gload_lds16(A + (size_t)(m0 + row) * H_DIM + k0 + ((c8p ^ (row & 7)) << 3),
                  &lds[bufbase + gbase * 8]);
    } else {      // B granule (row 0..127)
      const int gb = g - 2048, rb = gbase - 2048;
      const int row = gb >> 3, c8p = gb & 7;
      gload_lds16(W + (size_t)(v0 + row) * H_DIM + k0 + ((c8p ^ (row & 7)) << 3),
                  &lds[bufbase + 16384 + rb * 8]);
    }
  }
}

// One phase: ds-read fragments for k-subtile K2, optionally issue 3 prefetch
// loads, barrier, lgkmcnt(0), 16 MFMA under setprio, optional vmcnt gate.
// GATE: -1 none, 6 counted, 0 drain (tail only).
template <int K2, bool STAGE, int GATE>
__device__ __forceinline__ void phase(short* lds, int cbase,
                                      const short* __restrict__ A,
                                      const short* __restrict__ W, int nbase,
                                      int m0, int v0, int kpre, int wave,
                                      int lane, int lrow, int lk,
                                      f32x4 (&acc)[4][4], int wm4, int wn2) {
  short8 av[4], bv[4];
#pragma unroll
  for (int f = 0; f < 4; ++f) {
    int ar = wm4 * 64 + f * 16 + lrow;
    av[f] = *reinterpret_cast<const short8*>(
        &lds[cbase + ar * 64 + (((K2 * 4 + lk) ^ (ar & 7)) << 3)]);
    int br = wn2 * 64 + f * 16 + lrow;
    bv[f] = *reinterpret_cast<const short8*>(
        &lds[cbase + 16384 + br * 64 + (((K2 * 4 + lk) ^ (br & 7)) << 3)]);
  }
  if (STAGE) stage_tile<(K2 == 0) ? 0 : 3>(A, W, lds, nbase, m0, v0, kpre, wave, lane);
  __builtin_amdgcn_sched_barrier(0);
  __builtin_amdgcn_s_barrier();
  asm volatile("s_waitcnt lgkmcnt(0)" ::: "memory");
  __builtin_amdgcn_sched_barrier(0);
  __builtin_amdgcn_s_setprio(1);
#pragma unroll
  for (int fm = 0; fm < 4; ++fm)
#pragma unroll
    for (int fn = 0; fn < 4; ++fn)
      acc[fm][fn] = __builtin_amdgcn_mfma_f32_16x16x32_bf16(av[fm], bv[fn],
                                                            acc[fm][fn], 0, 0, 0);
  __builtin_amdgcn_s_setprio(0);
  if (GATE == 6) asm volatile("s_waitcnt vmcnt(6)" ::: "memory");
  if (GATE == 0) asm volatile("s_waitcnt vmcnt(0)" ::: "memory");
  __builtin_amdgcn_sched_barrier(0);
  __builtin_amdgcn_s_barrier();
}

__global__ __launch_bounds__(512, 2) void gemm_logits(
    const short* __restrict__ As, const short* __restrict__ At,
    const short* __restrict__ Ws, const short* __restrict__ Wt,
    short* __restrict__ Lgs, short* __restrict__ Lgt) {
  __shared__ short lds[3 * TILE_SH];  // 144 KiB

  // XCD-aware bijective chunk swizzle (4000 % 8 == 0), then decompose with
  // V-block fastest so consecutive blocks share the 1 MB A panel (L2-hot)
  // and stream W once through LLC.
  int gid = blockIdx.x;
  int swz = (gid & 7) * 500 + (gid >> 3);
  int gemm = swz / 2000;
  int rem = swz - gemm * 2000;
  int mblk = rem / 250;
  int vblk = rem - mblk * 250;
  const short* A = gemm ? At : As;
  const short* W = gemm ? Wt : Ws;
  short* L = gemm ? Lgt : Lgs;
  const int m0 = mblk * 256, v0 = vblk * 128;

  const int tid = threadIdx.x;
  const int wave = tid >> 6, lane = tid & 63;
  const int lrow = lane & 15, lk = lane >> 4;
  const int wm4 = wave >> 1, wn2 = wave & 1;

  f32x4 acc[4][4];
#pragma unroll
  for (int i = 0; i < 4; ++i)
#pragma unroll
    for (int j = 0; j < 4; ++j) acc[i][j] = (f32x4){0.f, 0.f, 0.f, 0.f};

  // Prologue: stage tiles 0 and 1; wait tile 0 landed (vmcnt(6) leaves tile
  // 1's 6 loads in flight).
  stage_tile<0>(A, W, lds, 0, m0, v0, 0, wave, lane);
  stage_tile<3>(A, W, lds, 0, m0, v0, 0, wave, lane);
  stage_tile<0>(A, W, lds, TILE_SH, m0, v0, 64, wave, lane);
  stage_tile<3>(A, W, lds, TILE_SH, m0, v0, 64, wave, lane);
  asm volatile("s_waitcnt vmcnt(6)" ::: "memory");
  __builtin_amdgcn_s_barrier();

  // Main loop: iteration i computes tile i from buf[i%3], stages tile i+2
  // into buf[(i+2)%3] (freed at end of iteration i-1). Gate vmcnt(6) once
  // per tile: tile i+1 landed, tile i+2's 6 loads stay in flight.
  int cur = 0;
  for (int i = 0; i < 30; ++i) {
    int nb = cur + 2; if (nb >= 3) nb -= 3;
    const int cbase = cur * TILE_SH, nbase = nb * TILE_SH;
    const int kpre = (i + 2) * 64;
    phase<0, true, -1>(lds, cbase, A, W, nbase, m0, v0, kpre, wave, lane, lrow, lk, acc, wm4, wn2);
    phase<1, true, 6>(lds, cbase, A, W, nbase, m0, v0, kpre, wave, lane, lrow, lk, acc, wm4, wn2);
    cur = (cur == 2) ? 0 : cur + 1;
  }
  // Tile 30: no prefetch; drain so tile 31 is fully landed.
  {
    const int cbase = cur * TILE_SH;
    phase<0, false, -1>(lds, cbase, A, W, 0, m0, v0, 0, wave, lane, lrow, lk, acc, wm4, wn2);
    phase<1, false, 0>(lds, cbase, A, W, 0, m0, v0, 0, wave, lane, lrow, lk, acc, wm4, wn2);
    cur = (cur == 2) ? 0 : cur + 1;
  }
  // Tile 31: last tile, no gate needed.
  {
    const int cbase = cur * TILE_SH;
    phase<0, false, -1>(lds, cbase, A, W, 0, m0, v0, 0, wave, lane, lrow, lk, acc, wm4, wn2);
    phase<1, false, -1>(lds, cbase, A, W, 0, m0, v0, 0, wave, lane, lrow, lk, acc, wm4, wn2);
  }

  // Epilogue: C/D layout col=lane&15, row=(lane>>4)*4+j (m89-verified).
#pragma unroll
  for (int fm = 0; fm < 4; ++fm) {
#pragma unroll
    for (int fn = 0; fn < 4; ++fn) {
      int gm = m0 + wm4 * 64 + fm * 16 + (lane >> 4) * 4;
      int gv = v0 + wn2 * 64 + fn * 16 + (lane & 15);
#pragma unroll
      for (int j = 0; j < 4; ++j)
        L[(size_t)(gm + j) * V_DIM + gv] = f2b(acc[fm][fn][j]);
    }
  }
}

// ---------------- fused per-row logsumexp + JSD ---------------------------
__device__ __forceinline__ float block_max(float v, float* red, int tid) {
#pragma unroll
  for (int o = 32; o; o >>= 1) v = fmaxf(v, __shfl_xor(v, o));
  if ((tid & 63) == 0) red[tid >> 6] = v;
  __syncthreads();
  v = fmaxf(fmaxf(red[0], red[1]), fmaxf(red[2], red[3]));
  __syncthreads();
  return v;
}
__device__ __forceinline__ float block_sum(float v, float* red, int tid) {
#pragma unroll
  for (int o = 32; o; o >>= 1) v += __shfl_xor(v, o);
  if ((tid & 63) == 0) red[tid >> 6] = v;
  __syncthreads();
  v = red[0] + red[1] + red[2] + red[3];
  __syncthreads();
  return v;
}

__global__ __launch_bounds__(256) void rows_jsd(const short* __restrict__ Lgs,
                                                const short* __restrict__ Lgt,
                                                float* __restrict__ partials) {
  const int n = blockIdx.x;
  const int tid = threadIdx.x;
  const short* rs = Lgs + (size_t)n * V_DIM;
  const short* rt = Lgt + (size_t)n * V_DIM;
  __shared__ float red[4];

  float ms = -1e30f, mt = -1e30f;
  for (int v = tid * 8; v < V_DIM; v += 2048) {
    short8 xs = *reinterpret_cast<const short8*>(rs + v);
    short8 xt = *reinterpret_cast<const short8*>(rt + v);
#pragma unroll
    for (int j = 0; j < 8; ++j) {
      ms = fmaxf(ms, bf2f(xs[j]));
      mt = fmaxf(mt, bf2f(xt[j]));
    }
  }
  ms = block_max(ms, red, tid);
  mt = block_max(mt, red, tid);

  float ss = 0.f, st = 0.f;
  for (int v = tid * 8; v < V_DIM; v += 2048) {
    short8 xs = *reinterpret_cast<const short8*>(rs + v);
    short8 xt = *reinterpret_cast<const short8*>(rt + v);
#pragma unroll
    for (int j = 0; j < 8; ++j) {
      ss += __expf(bf2f(xs[j]) - ms);
      st += __expf(bf2f(xt[j]) - mt);
    }
  }
  ss = block_sum(ss, red, tid);
  st = block_sum(st, red, tid);
  const float zq = ms + __logf(ss);  // student logsumexp
  const float zp = mt + __logf(st);  // teacher logsumexp

  float acc = 0.f;
  for (int v = tid * 8; v < V_DIM; v += 2048) {
    short8 xs = *reinterpret_cast<const short8*>(rs + v);
    short8 xt = *reinterpret_cast<const short8*>(rt + v);
#pragma unroll
    for (int j = 0; j < 8; ++j) {
      float lq = bf2f(xs[j]) - zq;
      float lp = bf2f(xt[j]) - zp;
      float q = __expf(lq), p = __expf(lp);
      float m = p + BETA * (q - p);
      float lm = __logf(m);
      acc += BETA * (p * (lp - lm)) + (1.f - BETA) * (q * (lq - lm));
    }
  }
  acc = block_sum(acc, red, tid);
  if (tid == 0) partials[n] = acc;
}

__global__ __launch_bounds__(256) void final_reduce(const float* __restrict__ partials,
                                                    int nb, float* __restrict__ out) {
  float s = 0.f;
  for (int i = threadIdx.x; i < nb; i += 256) s += partials[i];
#pragma unroll
  for (int o = 32; o; o >>= 1) s += __shfl_xor(s, o);
  __shared__ float red[4];
  if ((threadIdx.x & 63) == 0) red[threadIdx.x >> 6] = s;
  __syncthreads();
  if (threadIdx.x == 0) out[0] = (red[0] + red[1] + red[2] + red[3]) / (float)N_TOK;
}

// ---------------- launch ---------------------------------------------------
extern "C" void kernel_launch(void* const* d_in, const int* in_sizes, int n_in,
                              void* d_out, int out_size, void* d_ws, size_t ws_size,
                              hipStream_t stream) {
  const float* s_in = (const float*)d_in[0];
  const float* t_in = (const float*)d_in[1];
  const float* w_s  = (const float*)d_in[2];
  const float* w_t  = (const float*)d_in[3];
  float* out = (float*)d_out;

  char* ws = (char*)d_ws;
  size_t off = 0;
  auto alloc = [&](size_t bytes) {
    char* p = ws + off;
    off += (bytes + 255) & ~(size_t)255;
    return p;
  };
  short* Abf_s = (short*)alloc((size_t)N_TOK * H_DIM * 2);
  short* Abf_t = (short*)alloc((size_t)N_TOK * H_DIM * 2);
  short* Wbf_s = (short*)alloc((size_t)V_DIM * H_DIM * 2);
  short* Wbf_t = (short*)alloc((size_t)V_DIM * H_DIM * 2);
  short* Lg_s  = (short*)alloc((size_t)N_TOK * V_DIM * 2);
  short* Lg_t  = (short*)alloc((size_t)N_TOK * V_DIM * 2);
  float* partials = (float*)alloc(N_TOK * 4);

  if (off > ws_size) {
    hipMemsetAsync(d_out, 0xFF, sizeof(float), stream);
    return;
  }

  cvt_bf16<<<512, 256, 0, stream>>>(s_in, Abf_s, N_TOK * H_DIM / 8);
  cvt_bf16<<<512, 256, 0, stream>>>(t_in, Abf_t, N_TOK * H_DIM / 8);
  cvt_bf16<<<2048, 256, 0, stream>>>(w_s, Wbf_s, V_DIM * H_DIM / 8);
  cvt_bf16<<<2048, 256, 0, stream>>>(w_t, Wbf_t, V_DIM * H_DIM / 8);

  gemm_logits<<<4000, 512, 0, stream>>>(Abf_s, Abf_t, Wbf_s, Wbf_t, Lg_s, Lg_t);

  rows_jsd<<<N_TOK, 256, 0, stream>>>(Lg_s, Lg_t, partials);
  final_reduce<<<1, 256, 0, stream>>>(partials, N_TOK, out);
}

// Round 3
// 756.399 us; speedup vs baseline: 1.2178x; 1.1054x over previous
//
#include <hip/hip_runtime.h>
#include <hip/hip_bf16.h>

#define N_TOK 2048
#define H_DIM 2048
#define V_DIM 32000
#define BETA 0.5f

typedef __attribute__((ext_vector_type(8))) short short8;
typedef __attribute__((ext_vector_type(4))) float f32x4;

__device__ __forceinline__ float bf2f(short s) {
  unsigned int u = ((unsigned int)(unsigned short)s) << 16;
  return __uint_as_float(u);
}
__device__ __forceinline__ short f2b(float f) {
  __hip_bfloat16 h = __float2bfloat16(f);
  return *reinterpret_cast<short*>(&h);
}

// ---------------- fp32 -> bf16 conversion (vectorized, grid-stride) -------
__global__ __launch_bounds__(256) void cvt_bf16(const float* __restrict__ s,
                                                short* __restrict__ d, int n8) {
  int stride = gridDim.x * 256;
  for (int i = blockIdx.x * 256 + threadIdx.x; i < n8; i += stride) {
    const float4* sp = reinterpret_cast<const float4*>(s) + (size_t)i * 2;
    float4 a = sp[0], b = sp[1];
    short8 o;
    o[0] = f2b(a.x); o[1] = f2b(a.y); o[2] = f2b(a.z); o[3] = f2b(a.w);
    o[4] = f2b(b.x); o[5] = f2b(b.y); o[6] = f2b(b.z); o[7] = f2b(b.w);
    *reinterpret_cast<short8*>(d + (size_t)i * 8) = o;
  }
}

// ---------------- bf16 GEMM: logits[n,v] = sum_h A[n,h]*W[v,h] ------------
// m201-style 8-phase: BM=BN=256, BK=64, 8 waves (2M x 4N), wave tile 128x64.
// LDS: 2 buffers x (A 256x64 + B 256x64) bf16 = 128 KiB, XOR-swizzled via
// pre-swizzled global source (rule 21). Counted vmcnt gates, never drain.
#define ASH 16384      // A shorts per buffer (256 rows x 64 cols)
#define BUF_SH 32768   // shorts per buffer (A + B)

__device__ __forceinline__ void gload_lds16(const void* g, void* l) {
  __builtin_amdgcn_global_load_lds(
      (const __attribute__((address_space(1))) void*)g,
      (__attribute__((address_space(3))) void*)l, 16, 0, 0);
}

// One gload: operand load #i (64 rows x 64 cols bf16 = 8 KB across 8 waves).
#define STAGE_A(i) gload_lds16(Aby + aoff##i + kb, &lds[nbase + (i)*4096 + wbase])
#define STAGE_B(i) gload_lds16(Wby + boff##i + kb, &lds[nbase + ASH + (i)*4096 + wbase])

// Phase (KK = k-step 0/1, MH = m-half 0/1): ds_read fragments, issue staging
// (__VA_ARGS__), barrier, lgkmcnt(0), 16 MFMA under setprio, optional vmcnt
// gate (2 = counted steady state, 0 = tail drain), barrier.
#define PHASE(KK, MH, GATE, ...) do {                                          \
    const int xorc = (((KK) * 4 + lk) ^ lr7) << 3;                             \
    short8 av0 = *(const short8*)&lds[cbase + aro + (MH)*4096 + 0    + xorc];  \
    short8 av1 = *(const short8*)&lds[cbase + aro + (MH)*4096 + 1024 + xorc];  \
    short8 av2 = *(const short8*)&lds[cbase + aro + (MH)*4096 + 2048 + xorc];  \
    short8 av3 = *(const short8*)&lds[cbase + aro + (MH)*4096 + 3072 + xorc];  \
    if ((MH) == 0) {                                                           \
      bv[0] = *(const short8*)&lds[cbase + bro + 0    + xorc];                 \
      bv[1] = *(const short8*)&lds[cbase + bro + 1024 + xorc];                 \
      bv[2] = *(const short8*)&lds[cbase + bro + 2048 + xorc];                 \
      bv[3] = *(const short8*)&lds[cbase + bro + 3072 + xorc];                 \
    }                                                                          \
    __VA_ARGS__                                                                \
    __builtin_amdgcn_sched_barrier(0);                                         \
    __builtin_amdgcn_s_barrier();                                              \
    asm volatile("s_waitcnt lgkmcnt(0)" ::: "memory");                         \
    __builtin_amdgcn_sched_barrier(0);                                         \
    __builtin_amdgcn_s_setprio(1);                                             \
    acc[(MH)*4+0][0] = __builtin_amdgcn_mfma_f32_16x16x32_bf16(av0, bv[0], acc[(MH)*4+0][0],0,0,0); \
    acc[(MH)*4+0][1] = __builtin_amdgcn_mfma_f32_16x16x32_bf16(av0, bv[1], acc[(MH)*4+0][1],0,0,0); \
    acc[(MH)*4+0][2] = __builtin_amdgcn_mfma_f32_16x16x32_bf16(av0, bv[2], acc[(MH)*4+0][2],0,0,0); \
    acc[(MH)*4+0][3] = __builtin_amdgcn_mfma_f32_16x16x32_bf16(av0, bv[3], acc[(MH)*4+0][3],0,0,0); \
    acc[(MH)*4+1][0] = __builtin_amdgcn_mfma_f32_16x16x32_bf16(av1, bv[0], acc[(MH)*4+1][0],0,0,0); \
    acc[(MH)*4+1][1] = __builtin_amdgcn_mfma_f32_16x16x32_bf16(av1, bv[1], acc[(MH)*4+1][1],0,0,0); \
    acc[(MH)*4+1][2] = __builtin_amdgcn_mfma_f32_16x16x32_bf16(av1, bv[2], acc[(MH)*4+1][2],0,0,0); \
    acc[(MH)*4+1][3] = __builtin_amdgcn_mfma_f32_16x16x32_bf16(av1, bv[3], acc[(MH)*4+1][3],0,0,0); \
    acc[(MH)*4+2][0] = __builtin_amdgcn_mfma_f32_16x16x32_bf16(av2, bv[0], acc[(MH)*4+2][0],0,0,0); \
    acc[(MH)*4+2][1] = __builtin_amdgcn_mfma_f32_16x16x32_bf16(av2, bv[1], acc[(MH)*4+2][1],0,0,0); \
    acc[(MH)*4+2][2] = __builtin_amdgcn_mfma_f32_16x16x32_bf16(av2, bv[2], acc[(MH)*4+2][2],0,0,0); \
    acc[(MH)*4+2][3] = __builtin_amdgcn_mfma_f32_16x16x32_bf16(av2, bv[3], acc[(MH)*4+2][3],0,0,0); \
    acc[(MH)*4+3][0] = __builtin_amdgcn_mfma_f32_16x16x32_bf16(av3, bv[0], acc[(MH)*4+3][0],0,0,0); \
    acc[(MH)*4+3][1] = __builtin_amdgcn_mfma_f32_16x16x32_bf16(av3, bv[1], acc[(MH)*4+3][1],0,0,0); \
    acc[(MH)*4+3][2] = __builtin_amdgcn_mfma_f32_16x16x32_bf16(av3, bv[2], acc[(MH)*4+3][2],0,0,0); \
    acc[(MH)*4+3][3] = __builtin_amdgcn_mfma_f32_16x16x32_bf16(av3, bv[3], acc[(MH)*4+3][3],0,0,0); \
    __builtin_amdgcn_s_setprio(0);                                             \
    if ((GATE) == 2) asm volatile("s_waitcnt vmcnt(2)" ::: "memory");          \
    if ((GATE) == 0) asm volatile("s_waitcnt vmcnt(0)" ::: "memory");          \
    __builtin_amdgcn_sched_barrier(0);                                         \
    __builtin_amdgcn_s_barrier();                                              \
  } while (0)

__global__ __launch_bounds__(512, 2) void gemm_logits(
    const short* __restrict__ As, const short* __restrict__ At,
    const short* __restrict__ Ws, const short* __restrict__ Wt,
    short* __restrict__ Lgs, short* __restrict__ Lgt) {
  __shared__ short lds[2 * BUF_SH];  // 128 KiB

  // Bijective XCD chunking (2000 % 8 == 0), then mblk-FASTEST within each
  // gemm: 8 consecutive blocks share one 1 MB W panel (L2-hot); W streams
  // through HBM exactly once; all A panels (16 MB) live in LLC.
  const int gid = blockIdx.x;
  const int swz = (gid & 7) * 250 + (gid >> 3);
  const int gemm = swz >= 1000;
  const int rem = swz - gemm * 1000;
  const int vblk = rem >> 3, mblk = rem & 7;
  const short* A = gemm ? At : As;
  const short* W = gemm ? Wt : Ws;
  short* L = gemm ? Lgt : Lgs;
  const int m0 = mblk * 256, v0 = vblk * 256;

  const int tid = threadIdx.x;
  const int wave = tid >> 6, lane = tid & 63;
  const int lrow = lane & 15, lk = lane >> 4, lr7 = lrow & 7;
  const int wr = wave >> 2, wc = wave & 3;   // 2M x 4N wave grid
  const int wbase = wave * 512;              // gload LDS granule base (shorts)
  const int aro = (wr * 128 + lrow) * 64;    // A ds_read row base (shorts)
  const int bro = ASH + (wc * 64 + lrow) * 64;
  const char* Aby = (const char*)A;
  const char* Wby = (const char*)W;

  // Pre-swizzled per-lane global source offsets (bytes) for the 8 loads of a
  // K-tile; per tile only kb (= k0*2) advances.
  unsigned aoff0, aoff1, aoff2, aoff3, boff0, boff1, boff2, boff3;
  {
#define MKOFF(i, dstA, dstB)                                                   \
    {                                                                          \
      int g = (i) * 512 + wave * 64 + lane;                                    \
      int row = g >> 3, c8p = g & 7, col = (c8p ^ (row & 7)) << 3;             \
      dstA = (unsigned)((((m0) + row) * H_DIM + col) * 2);                     \
      dstB = (unsigned)((((v0) + row) * H_DIM + col) * 2);                     \
    }
    MKOFF(0, aoff0, boff0) MKOFF(1, aoff1, boff1)
    MKOFF(2, aoff2, boff2) MKOFF(3, aoff3, boff3)
#undef MKOFF
  }

  f32x4 acc[8][4];
#pragma unroll
  for (int i = 0; i < 8; ++i)
#pragma unroll
    for (int j = 0; j < 4; ++j) acc[i][j] = (f32x4){0.f, 0.f, 0.f, 0.f};
  short8 bv[4];

  // Prologue: stage tiles 0 and 1 (16 loads); wait tile 0 landed (8 remain).
  { const int nbase = 0, kb = 0;
    STAGE_A(0); STAGE_A(2); STAGE_B(0); STAGE_B(1);
    STAGE_B(2); STAGE_B(3); STAGE_A(1); STAGE_A(3); }
  { const int nbase = BUF_SH, kb = 128;
    STAGE_A(0); STAGE_A(2); STAGE_B(0); STAGE_B(1);
    STAGE_B(2); STAGE_B(3); STAGE_A(1); STAGE_A(3); }
  asm volatile("s_waitcnt vmcnt(8)" ::: "memory");
  __builtin_amdgcn_s_barrier();

  // Tile 0: tile 1 already fully staged in prologue -> no staging here.
  // End-P4 gate vmcnt(2): tile 1's first 6 loads landed (A1,A3 in flight).
  { const int cbase = 0;
    PHASE(0, 0, -1, (void)0;);
    PHASE(0, 1, -1, (void)0;);
    PHASE(1, 0, -1, (void)0;);
    PHASE(1, 1,  2, (void)0;);
  }
  // Tiles 1..30: stage tile t+1 (2 loads/phase). End-P1 gate vmcnt(2):
  // current tile's A1,A3 landed. End-P4 gate vmcnt(2): next tile's first 6.
  for (int t = 1; t <= 30; ++t) {
    const int cbase = (t & 1) * BUF_SH;
    const int nbase = cbase ^ BUF_SH;
    const int kb = (t + 1) * 128;
    PHASE(0, 0,  2, STAGE_A(0); STAGE_A(2););
    PHASE(0, 1, -1, STAGE_B(0); STAGE_B(1););
    PHASE(1, 0, -1, STAGE_B(2); STAGE_B(3););
    PHASE(1, 1,  2, STAGE_A(1); STAGE_A(3););
  }
  // Tile 31: drain the last 2 in-flight loads (A1,A3) at end-P1.
  { const int cbase = BUF_SH;
    PHASE(0, 0,  0, (void)0;);
    PHASE(0, 1, -1, (void)0;);
    PHASE(1, 0, -1, (void)0;);
    PHASE(1, 1, -1, (void)0;);
  }

  // Epilogue: C/D layout col=lane&15, row=(lane>>4)*4+j (m89-verified).
#pragma unroll
  for (int fm = 0; fm < 8; ++fm) {
#pragma unroll
    for (int fn = 0; fn < 4; ++fn) {
      int gm = m0 + wr * 128 + fm * 16 + (lane >> 4) * 4;
      int gv = v0 + wc * 64 + fn * 16 + (lane & 15);
#pragma unroll
      for (int j = 0; j < 4; ++j)
        L[(size_t)(gm + j) * V_DIM + gv] = f2b(acc[fm][fn][j]);
    }
  }
}

// ---------------- fused per-row logsumexp + JSD ---------------------------
__device__ __forceinline__ float block_max(float v, float* red, int tid) {
#pragma unroll
  for (int o = 32; o; o >>= 1) v = fmaxf(v, __shfl_xor(v, o));
  if ((tid & 63) == 0) red[tid >> 6] = v;
  __syncthreads();
  v = fmaxf(fmaxf(red[0], red[1]), fmaxf(red[2], red[3]));
  __syncthreads();
  return v;
}
__device__ __forceinline__ float block_sum(float v, float* red, int tid) {
#pragma unroll
  for (int o = 32; o; o >>= 1) v += __shfl_xor(v, o);
  if ((tid & 63) == 0) red[tid >> 6] = v;
  __syncthreads();
  v = red[0] + red[1] + red[2] + red[3];
  __syncthreads();
  return v;
}

__global__ __launch_bounds__(256) void rows_jsd(const short* __restrict__ Lgs,
                                                const short* __restrict__ Lgt,
                                                float* __restrict__ partials) {
  const int n = blockIdx.x;
  const int tid = threadIdx.x;
  const short* rs = Lgs + (size_t)n * V_DIM;
  const short* rt = Lgt + (size_t)n * V_DIM;
  __shared__ float red[4];

  float ms = -1e30f, mt = -1e30f;
  for (int v = tid * 8; v < V_DIM; v += 2048) {
    short8 xs = *reinterpret_cast<const short8*>(rs + v);
    short8 xt = *reinterpret_cast<const short8*>(rt + v);
#pragma unroll
    for (int j = 0; j < 8; ++j) {
      ms = fmaxf(ms, bf2f(xs[j]));
      mt = fmaxf(mt, bf2f(xt[j]));
    }
  }
  ms = block_max(ms, red, tid);
  mt = block_max(mt, red, tid);

  float ss = 0.f, st = 0.f;
  for (int v = tid * 8; v < V_DIM; v += 2048) {
    short8 xs = *reinterpret_cast<const short8*>(rs + v);
    short8 xt = *reinterpret_cast<const short8*>(rt + v);
#pragma unroll
    for (int j = 0; j < 8; ++j) {
      ss += __expf(bf2f(xs[j]) - ms);
      st += __expf(bf2f(xt[j]) - mt);
    }
  }
  ss = block_sum(ss, red, tid);
  st = block_sum(st, red, tid);
  const float zq = ms + __logf(ss);  // student logsumexp
  const float zp = mt + __logf(st);  // teacher logsumexp

  float acc = 0.f;
  for (int v = tid * 8; v < V_DIM; v += 2048) {
    short8 xs = *reinterpret_cast<const short8*>(rs + v);
    short8 xt = *reinterpret_cast<const short8*>(rt + v);
#pragma unroll
    for (int j = 0; j < 8; ++j) {
      float lq = bf2f(xs[j]) - zq;
      float lp = bf2f(xt[j]) - zp;
      float q = __expf(lq), p = __expf(lp);
      float m = p + BETA * (q - p);
      float lm = __logf(m);
      acc += BETA * (p * (lp - lm)) + (1.f - BETA) * (q * (lq - lm));
    }
  }
  acc = block_sum(acc, red, tid);
  if (tid == 0) partials[n] = acc;
}

__global__ __launch_bounds__(256) void final_reduce(const float* __restrict__ partials,
                                                    int nb, float* __restrict__ out) {
  float s = 0.f;
  for (int i = threadIdx.x; i < nb; i += 256) s += partials[i];
#pragma unroll
  for (int o = 32; o; o >>= 1) s += __shfl_xor(s, o);
  __shared__ float red[4];
  if ((threadIdx.x & 63) == 0) red[threadIdx.x >> 6] = s;
  __syncthreads();
  if (threadIdx.x == 0) out[0] = (red[0] + red[1] + red[2] + red[3]) / (float)N_TOK;
}

// ---------------- launch ---------------------------------------------------
extern "C" void kernel_launch(void* const* d_in, const int* in_sizes, int n_in,
                              void* d_out, int out_size, void* d_ws, size_t ws_size,
                              hipStream_t stream) {
  const float* s_in = (const float*)d_in[0];
  const float* t_in = (const float*)d_in[1];
  const float* w_s  = (const float*)d_in[2];
  const float* w_t  = (const float*)d_in[3];
  float* out = (float*)d_out;

  char* ws = (char*)d_ws;
  size_t off = 0;
  auto alloc = [&](size_t bytes) {
    char* p = ws + off;
    off += (bytes + 255) & ~(size_t)255;
    return p;
  };
  short* Abf_s = (short*)alloc((size_t)N_TOK * H_DIM * 2);
  short* Abf_t = (short*)alloc((size_t)N_TOK * H_DIM * 2);
  short* Wbf_s = (short*)alloc((size_t)V_DIM * H_DIM * 2);
  short* Wbf_t = (short*)alloc((size_t)V_DIM * H_DIM * 2);
  short* Lg_s  = (short*)alloc((size_t)N_TOK * V_DIM * 2);
  short* Lg_t  = (short*)alloc((size_t)N_TOK * V_DIM * 2);
  float* partials = (float*)alloc(N_TOK * 4);

  if (off > ws_size) {
    hipMemsetAsync(d_out, 0xFF, sizeof(float), stream);
    return;
  }

  cvt_bf16<<<512, 256, 0, stream>>>(s_in, Abf_s, N_TOK * H_DIM / 8);
  cvt_bf16<<<512, 256, 0, stream>>>(t_in, Abf_t, N_TOK * H_DIM / 8);
  cvt_bf16<<<2048, 256, 0, stream>>>(w_s, Wbf_s, V_DIM * H_DIM / 8);
  cvt_bf16<<<2048, 256, 0, stream>>>(w_t, Wbf_t, V_DIM * H_DIM / 8);

  gemm_logits<<<2000, 512, 0, stream>>>(Abf_s, Abf_t, Wbf_s, Wbf_t, Lg_s, Lg_t);

  rows_jsd<<<N_TOK, 256, 0, stream>>>(Lg_s, Lg_t, partials);
  final_reduce<<<1, 256, 0, stream>>>(partials, N_TOK, out);
}